// Round 14
// baseline (694.484 us; speedup 1.0000x reference)
//
#include <hip/hip_runtime.h>
#include <cmath>

constexpr int F1 = 128;  // input features
constexpr int H  = 64;   // hidden
constexpr int NC = 40;   // classes
constexpr int NCOPY = 8; // per-XCD histogram/cursor copies

constexpr int SCAN_TPB = 256;
constexpr int SCAN_IPT = 8;
constexpr int SCAN_EPB = SCAN_TPB * SCAN_IPT;  // 2048 elements per block

// ---- bf16 helpers (RNE pack, cheap unpack) ----
__device__ inline unsigned short f2bf(float f) {
    union { float f; unsigned u; } v; v.f = f;
    return (unsigned short)((v.u + 0x7FFFu + ((v.u >> 16) & 1u)) >> 16);
}
__device__ inline float bflo(unsigned p) { union { float f; unsigned u; } v; v.u = p << 16; return v.f; }
__device__ inline float bfhi(unsigned p) { union { float f; unsigned u; } v; v.u = p & 0xFFFF0000u; return v.f; }
__device__ inline void unpack8(uint4 raw, float* d) {
    d[0] = bflo(raw.x); d[1] = bfhi(raw.x); d[2] = bflo(raw.y); d[3] = bfhi(raw.y);
    d[4] = bflo(raw.z); d[5] = bfhi(raw.z); d[6] = bflo(raw.w); d[7] = bfhi(raw.w);
}

// ---- inverse sigmas ----
__global__ void isg_kernel(const float* __restrict__ s1, float* __restrict__ i1,
                           const float* __restrict__ s2, float* __restrict__ i2) {
    int i = threadIdx.x;
    if (i < F1) i1[i] = 1.0f / s1[i];
    if (i < H)  i2[i] = 1.0f / s2[i];
}

// ---- single-sweep degree histogram into per-XCD copies (blocks < cntBlocks) + u1 prep ----
// copy = bid & 7: under round-robin dispatch each copy's lines stay on one XCD (perf
// heuristic only — any mapping is correct). Edge e is handled by block e/256 — the
// SAME mapping is used in build1_kernel so each edge uses the same copy's cursor.
__global__ void count1_prep_kernel(const int* __restrict__ row, const int* __restrict__ col,
                                   int* __restrict__ cnt8, int E, int N, int cntBlocks,
                                   const float* __restrict__ x, const float* __restrict__ isg,
                                   unsigned short* __restrict__ u, size_t n8) {
    int bid = blockIdx.x;
    if (bid < cntBlocks) {
        int e = bid * 256 + threadIdx.x;
        if (e < E) {
            int* cnt = cnt8 + (size_t)(bid & (NCOPY - 1)) * 2 * N;
            atomicAdd(&cnt[row[e]], 1);
            atomicAdd(&cnt[N + col[e]], 1);
        }
    } else {
        size_t idx = (size_t)(bid - cntBlocks) * 256 + threadIdx.x;
        if (idx >= n8) return;
        size_t base = idx * 8;
        int fk = (int)(base % (size_t)F1);
        float4 a0 = *(const float4*)&x[base];
        float4 a1 = *(const float4*)&x[base + 4];
        float4 s0 = *(const float4*)&isg[fk];
        float4 s1 = *(const float4*)&isg[fk + 4];
        uint4 p4;
        p4.x = (unsigned)f2bf(a0.x * s0.x) | ((unsigned)f2bf(a0.y * s0.y) << 16);
        p4.y = (unsigned)f2bf(a0.z * s0.z) | ((unsigned)f2bf(a0.w * s0.w) << 16);
        p4.z = (unsigned)f2bf(a1.x * s1.x) | ((unsigned)f2bf(a1.y * s1.y) << 16);
        p4.w = (unsigned)f2bf(a1.z * s1.z) | ((unsigned)f2bf(a1.w * s1.w) << 16);
        *(uint4*)&u[base] = p4;
    }
}

// ---- multi-block exclusive scan over summed histogram (M = 2N elements, 8 copies) ----
__global__ void scan_partial_kernel(const int* __restrict__ cnt8, int* __restrict__ bsum, int M) {
    __shared__ int red[SCAN_TPB];
    int t = threadIdx.x;
    int i0 = blockIdx.x * SCAN_EPB + t * SCAN_IPT;
    int s = 0;
#pragma unroll
    for (int k = 0; k < SCAN_IPT; ++k) {
        int i = i0 + k;
        if (i < M) {
#pragma unroll
            for (int c = 0; c < NCOPY; ++c) s += cnt8[(size_t)c * M + i];
        }
    }
    red[t] = s;
    __syncthreads();
    for (int off = SCAN_TPB / 2; off > 0; off >>= 1) {
        if (t < off) red[t] += red[t + off];
        __syncthreads();
    }
    if (t == 0) bsum[blockIdx.x] = red[0];
}

__global__ void scan_offsets_kernel(int* __restrict__ bsum, int nb,
                                    int* __restrict__ rowptrO, int* __restrict__ rowptrI,
                                    int N, int E) {
    __shared__ int sh[1024];
    int t = threadIdx.x;
    sh[t] = (t < nb) ? bsum[t] : 0;
    __syncthreads();
    for (int off = 1; off < 1024; off <<= 1) {
        int v = (t >= off) ? sh[t - off] : 0;
        __syncthreads();
        sh[t] += v;
        __syncthreads();
    }
    if (t < nb) bsum[t] = (t > 0) ? sh[t - 1] : 0;  // exclusive block offsets
    if (t == 0) { rowptrO[N] = E; rowptrI[N] = E; }
}

// ---- final scan: rowptr + dis + PER-COPY cursor bases (cur8[c][i] = base + sum_{q<c} cnt_q[i]) ----
__global__ void scan_final_kernel(const int* __restrict__ cnt8, int* __restrict__ cur8,
                                  const int* __restrict__ bsum,
                                  int* __restrict__ rowptrO, int* __restrict__ rowptrI,
                                  float* __restrict__ dis, int N, int E) {
    __shared__ int sh[SCAN_TPB];
    int t = threadIdx.x;
    int M = 2 * N;
    int i0 = blockIdx.x * SCAN_EPB + t * SCAN_IPT;
    int tot[SCAN_IPT], pre[SCAN_IPT];
    int run = 0;
#pragma unroll
    for (int k = 0; k < SCAN_IPT; ++k) {
        int i = i0 + k;
        int s = 0;
        if (i < M) {
#pragma unroll
            for (int c = 0; c < NCOPY; ++c) s += cnt8[(size_t)c * M + i];
        }
        tot[k] = s;
        pre[k] = run;
        run += s;
    }
    sh[t] = run;
    __syncthreads();
    for (int off = 1; off < SCAN_TPB; off <<= 1) {
        int v = (t >= off) ? sh[t - off] : 0;
        __syncthreads();
        sh[t] += v;
        __syncthreads();
    }
    int toff = ((t > 0) ? sh[t - 1] : 0) + bsum[blockIdx.x];
#pragma unroll
    for (int k = 0; k < SCAN_IPT; ++k) {
        int i = i0 + k;
        if (i < M) {
            int val = toff + pre[k];
            int base;
            if (i < N) {
                rowptrO[i] = val;
                dis[i] = rsqrtf((float)(tot[k] + 1));   // deg includes self-loop
                base = val;
            } else {
                rowptrI[i - N] = val - E;
                base = val - E;
            }
            int b = base;
#pragma unroll
            for (int c = 0; c < NCOPY; ++c) {
                cur8[(size_t)c * M + i] = b;
                b += cnt8[(size_t)c * M + i];
            }
        }
    }
}

// ---- single-sweep adjacency fill via per-copy cursors; entries carry (neighbor, norm) ----
__global__ void build1_kernel(const int* __restrict__ row, const int* __restrict__ col,
                              int* __restrict__ cur8,
                              int2* __restrict__ adjO2, int2* __restrict__ adjI2,
                              const float* __restrict__ dis, int E, int N) {
    int bid = blockIdx.x;
    int e = bid * 256 + threadIdx.x;
    if (e >= E) return;
    int* cur = cur8 + (size_t)(bid & (NCOPY - 1)) * 2 * N;   // SAME copy mapping as count
    int r = row[e], c = col[e];
    float nrm = dis[r] * dis[c];
    int nb = __float_as_int(nrm);
    adjO2[atomicAdd(&cur[r], 1)] = make_int2(c, nb);
    adjI2[atomicAdd(&cur[N + c], 1)] = make_int2(r, nb);
}

// ---- fused: mask gather (bf16 u rows; adj2 gives nbr+norm; P=2 named-scalar prefetch)
//      + apply (x = u*sigma) -> LDS Xs -> GEMM (2 waves x 4 rows, W-read amortized) ----
template<int F, int O, int R>
__global__ void fused_mask_gemm_kernel(const int* __restrict__ rowptr, const int2* __restrict__ adj2,
                                       const float* __restrict__ sig,
                                       const unsigned short* __restrict__ u,
                                       const float* __restrict__ W,
                                       unsigned short* __restrict__ Ybf, int N) {
    constexpr int NT = R * 64;
    constexpr int G = F / 8;        // lanes per row (uint4 = 8 bf16 each)
    constexpr int NPI = 64 / G;     // neighbors per wave-iteration
    __shared__ __align__(16) float Ws[F * O];
    __shared__ __align__(16) float Xs[R][F];
    int tid = threadIdx.x;
    for (int i = tid; i < F * O; i += NT) Ws[i] = W[i];
    int w = tid >> 6, lane = tid & 63;
    int h = lane / G, j = lane % G;
    int base = blockIdx.x * R;
    int r = base + w;
    if (r < N) {
        int beg = rowptr[r], end = rowptr[r + 1];
        float inv_deg = 1.0f / (float)(end - beg + 1);
        float ur[8], acc[8];
        unpack8(*(const uint4*)&u[(size_t)r * F + 8 * j], ur);
#pragma unroll
        for (int k = 0; k < 8; ++k) acc[k] = 0.0f;
        for (int t = beg; t < end; t += 2 * NPI) {
            int e0 = t + h, e1 = t + NPI + h;
            int2 a0 = adj2[min(e0, end - 1)];
            int2 a1 = adj2[min(e1, end - 1)];
            float n0 = (e0 < end) ? __int_as_float(a0.y) : 0.0f;
            float n1 = (e1 < end) ? __int_as_float(a1.y) : 0.0f;
            uint4 rw0 = *(const uint4*)&u[(size_t)a0.x * F + 8 * j];
            uint4 rw1 = *(const uint4*)&u[(size_t)a1.x * F + 8 * j];
            float uc[8];
            unpack8(rw0, uc);
#pragma unroll
            for (int q = 0; q < 8; ++q) {
                float d = uc[q] - ur[q];
                acc[q] = fmaf(n0 * d, d, acc[q]);
            }
            unpack8(rw1, uc);
#pragma unroll
            for (int q = 0; q < 8; ++q) {
                float d = uc[q] - ur[q];
                acc[q] = fmaf(n1 * d, d, acc[q]);
            }
        }
#pragma unroll
        for (int off = G; off < 64; off <<= 1) {
#pragma unroll
            for (int k = 0; k < 8; ++k) acc[k] += __shfl_xor(acc[k], off);
        }
        if (h == 0) {
            float4 s0 = *(const float4*)&sig[8 * j];
            float4 s1 = *(const float4*)&sig[8 * j + 4];
            float sg[8] = {s0.x, s0.y, s0.z, s0.w, s1.x, s1.y, s1.z, s1.w};
            float xm[8];
#pragma unroll
            for (int k = 0; k < 8; ++k) xm[k] = ur[k] * sg[k] * expf(-acc[k] * inv_deg);
            *(float4*)&Xs[w][8 * j]     = make_float4(xm[0], xm[1], xm[2], xm[3]);
            *(float4*)&Xs[w][8 * j + 4] = make_float4(xm[4], xm[5], xm[6], xm[7]);
        }
    } else if (h == 0) {
        *(float4*)&Xs[w][8 * j]     = make_float4(0.f, 0.f, 0.f, 0.f);
        *(float4*)&Xs[w][8 * j + 4] = make_float4(0.f, 0.f, 0.f, 0.f);
    }
    __syncthreads();
    // GEMM: waves 0,1 each compute 4 rows; lane = output column.
    if (w < 2) {
        int r0 = base + 4 * w;
        if (r0 < N && lane < O) {
            float a0 = 0.f, a1 = 0.f, a2 = 0.f, a3 = 0.f;
#pragma unroll
            for (int fq = 0; fq < F / 4; ++fq) {
                float4 x0 = *(const float4*)&Xs[4 * w + 0][4 * fq];
                float4 x1 = *(const float4*)&Xs[4 * w + 1][4 * fq];
                float4 x2 = *(const float4*)&Xs[4 * w + 2][4 * fq];
                float4 x3 = *(const float4*)&Xs[4 * w + 3][4 * fq];
                float w0 = Ws[(4 * fq + 0) * O + lane];
                float w1 = Ws[(4 * fq + 1) * O + lane];
                float w2 = Ws[(4 * fq + 2) * O + lane];
                float w3 = Ws[(4 * fq + 3) * O + lane];
                a0 = fmaf(x0.x, w0, a0); a0 = fmaf(x0.y, w1, a0); a0 = fmaf(x0.z, w2, a0); a0 = fmaf(x0.w, w3, a0);
                a1 = fmaf(x1.x, w0, a1); a1 = fmaf(x1.y, w1, a1); a1 = fmaf(x1.z, w2, a1); a1 = fmaf(x1.w, w3, a1);
                a2 = fmaf(x2.x, w0, a2); a2 = fmaf(x2.y, w1, a2); a2 = fmaf(x2.z, w2, a2); a2 = fmaf(x2.w, w3, a2);
                a3 = fmaf(x3.x, w0, a3); a3 = fmaf(x3.y, w1, a3); a3 = fmaf(x3.z, w2, a3); a3 = fmaf(x3.w, w3, a3);
            }
            float o0 = __shfl_xor(a0, 1);
            float o1 = __shfl_xor(a1, 1);
            float o2 = __shfl_xor(a2, 1);
            float o3 = __shfl_xor(a3, 1);
            if (!(lane & 1)) {
                *(unsigned*)&Ybf[(size_t)r0 * O + lane] = (unsigned)f2bf(a0) | ((unsigned)f2bf(o0) << 16);
                if (r0 + 1 < N) *(unsigned*)&Ybf[(size_t)(r0 + 1) * O + lane] = (unsigned)f2bf(a1) | ((unsigned)f2bf(o1) << 16);
                if (r0 + 2 < N) *(unsigned*)&Ybf[(size_t)(r0 + 2) * O + lane] = (unsigned)f2bf(a2) | ((unsigned)f2bf(o2) << 16);
                if (r0 + 3 < N) *(unsigned*)&Ybf[(size_t)(r0 + 3) * O + lane] = (unsigned)f2bf(a3) | ((unsigned)f2bf(o3) << 16);
            }
        }
    }
}

// ---- agg layer1: h = relu(sum nrm*xw_bf16 + dis^2*xw_self + b); writes ONLY u2=bf16(h*isg2) ----
__global__ void agg_relu_kernel(const int* __restrict__ rowptr, const int2* __restrict__ adj2,
                                const float* __restrict__ dis, const unsigned short* __restrict__ ybf,
                                const float* __restrict__ bias,
                                unsigned short* __restrict__ u2, const float* __restrict__ isg2, int N) {
    int c = blockIdx.x * (blockDim.x >> 6) + (threadIdx.x >> 6);
    if (c >= N) return;
    int lane = threadIdx.x & 63;
    int h = lane >> 3, j = lane & 7;
    int beg = rowptr[c], end = rowptr[c + 1];
    float acc[8];
#pragma unroll
    for (int k = 0; k < 8; ++k) acc[k] = 0.0f;
    for (int t = beg; t < end; t += 16) {
        int e0 = t + h, e1 = t + 8 + h;
        int2 a0 = adj2[min(e0, end - 1)];
        int2 a1 = adj2[min(e1, end - 1)];
        float n0 = (e0 < end) ? __int_as_float(a0.y) : 0.0f;
        float n1 = (e1 < end) ? __int_as_float(a1.y) : 0.0f;
        uint4 rw0 = *(const uint4*)&ybf[(size_t)a0.x * H + 8 * j];
        uint4 rw1 = *(const uint4*)&ybf[(size_t)a1.x * H + 8 * j];
        float v[8];
        unpack8(rw0, v);
#pragma unroll
        for (int q = 0; q < 8; ++q) acc[q] = fmaf(n0, v[q], acc[q]);
        unpack8(rw1, v);
#pragma unroll
        for (int q = 0; q < 8; ++q) acc[q] = fmaf(n1, v[q], acc[q]);
    }
#pragma unroll
    for (int off = 8; off < 64; off <<= 1) {
#pragma unroll
        for (int k = 0; k < 8; ++k) acc[k] += __shfl_xor(acc[k], off);
    }
    if (h == 0) {
        float dc = dis[c];
        float sv[8];
        unpack8(*(const uint4*)&ybf[(size_t)c * H + 8 * j], sv);
        float4 b0 = *(const float4*)&bias[8 * j];
        float4 b1v = *(const float4*)&bias[8 * j + 4];
        float bb[8] = {b0.x, b0.y, b0.z, b0.w, b1v.x, b1v.y, b1v.z, b1v.w};
        float4 s0 = *(const float4*)&isg2[8 * j];
        float4 s1 = *(const float4*)&isg2[8 * j + 4];
        float sg[8] = {s0.x, s0.y, s0.z, s0.w, s1.x, s1.y, s1.z, s1.w};
        float hv[8];
        float d2 = dc * dc;
#pragma unroll
        for (int k = 0; k < 8; ++k) hv[k] = fmaxf(fmaf(d2, sv[k], acc[k]) + bb[k], 0.0f);
        uint4 p;
        p.x = (unsigned)f2bf(hv[0] * sg[0]) | ((unsigned)f2bf(hv[1] * sg[1]) << 16);
        p.y = (unsigned)f2bf(hv[2] * sg[2]) | ((unsigned)f2bf(hv[3] * sg[3]) << 16);
        p.z = (unsigned)f2bf(hv[4] * sg[4]) | ((unsigned)f2bf(hv[5] * sg[5]) << 16);
        p.w = (unsigned)f2bf(hv[6] * sg[6]) | ((unsigned)f2bf(hv[7] * sg[7]) << 16);
        *(uint4*)&u2[(size_t)c * H + 8 * j] = p;
    }
}

// ---- agg layer2: out = log_softmax(sum nrm*xw2_bf16 + dis^2*self + b) over NC=40 ----
__global__ void agg_lsm_kernel(const int* __restrict__ rowptr, const int2* __restrict__ adj2,
                               const float* __restrict__ dis, const unsigned short* __restrict__ ybf,
                               const float* __restrict__ bias, float* __restrict__ out, int N) {
    int c = blockIdx.x * (blockDim.x >> 6) + (threadIdx.x >> 6);
    if (c >= N) return;
    int lane = threadIdx.x & 63;
    int h = lane >> 4, j = lane & 15;
    bool active = j < 10;
    int beg = rowptr[c], end = rowptr[c + 1];
    float a[4] = {0.f, 0.f, 0.f, 0.f};
    for (int t = beg; t < end; t += 8) {
        int e0 = t + h, e1 = t + 4 + h;
        int2 a0 = adj2[min(e0, end - 1)];
        int2 a1 = adj2[min(e1, end - 1)];
        float n0 = (e0 < end) ? __int_as_float(a0.y) : 0.0f;
        float n1 = (e1 < end) ? __int_as_float(a1.y) : 0.0f;
        uint2 rw0 = active ? *(const uint2*)&ybf[(size_t)a0.x * NC + 4 * j] : make_uint2(0u, 0u);
        uint2 rw1 = active ? *(const uint2*)&ybf[(size_t)a1.x * NC + 4 * j] : make_uint2(0u, 0u);
        a[0] = fmaf(n0, bflo(rw0.x), a[0]); a[1] = fmaf(n0, bfhi(rw0.x), a[1]);
        a[2] = fmaf(n0, bflo(rw0.y), a[2]); a[3] = fmaf(n0, bfhi(rw0.y), a[3]);
        a[0] = fmaf(n1, bflo(rw1.x), a[0]); a[1] = fmaf(n1, bfhi(rw1.x), a[1]);
        a[2] = fmaf(n1, bflo(rw1.y), a[2]); a[3] = fmaf(n1, bfhi(rw1.y), a[3]);
    }
#pragma unroll
    for (int off = 16; off < 64; off <<= 1) {
#pragma unroll
        for (int k = 0; k < 4; ++k) a[k] += __shfl_xor(a[k], off);
    }
    bool wr = (h == 0) && active;
    float v[4] = {-INFINITY, -INFINITY, -INFINITY, -INFINITY};
    if (wr) {
        float dc = dis[c];
        uint2 sr = *(const uint2*)&ybf[(size_t)c * NC + 4 * j];
        float sv[4] = {bflo(sr.x), bfhi(sr.x), bflo(sr.y), bfhi(sr.y)};
        float4 bb = *(const float4*)&bias[4 * j];
        float b4[4] = {bb.x, bb.y, bb.z, bb.w};
        float d2 = dc * dc;
#pragma unroll
        for (int k = 0; k < 4; ++k) v[k] = fmaf(d2, sv[k], a[k]) + b4[k];
    }
    float m = fmaxf(fmaxf(v[0], v[1]), fmaxf(v[2], v[3]));
#pragma unroll
    for (int off = 8; off > 0; off >>= 1) m = fmaxf(m, __shfl_xor(m, off));
    float s = wr ? (expf(v[0] - m) + expf(v[1] - m) + expf(v[2] - m) + expf(v[3] - m)) : 0.0f;
#pragma unroll
    for (int off = 8; off > 0; off >>= 1) s += __shfl_xor(s, off);
    float mls = m + logf(s);
    if (wr)
        *(float4*)&out[(size_t)c * NC + 4 * j] = make_float4(v[0] - mls, v[1] - mls, v[2] - mls, v[3] - mls);
}

extern "C" void kernel_launch(void* const* d_in, const int* in_sizes, int n_in,
                              void* d_out, int out_size, void* d_ws, size_t ws_size,
                              hipStream_t stream) {
    const float* x    = (const float*)d_in[0];
    const int*   ei   = (const int*)  d_in[1];
    const float* sig1 = (const float*)d_in[2];
    const float* W1   = (const float*)d_in[3];
    const float* b1   = (const float*)d_in[4];
    const float* sig2 = (const float*)d_in[5];
    const float* W2   = (const float*)d_in[6];
    const float* b2   = (const float*)d_in[7];
    float* out = (float*)d_out;

    const int N = in_sizes[0] / F1;
    const int E = in_sizes[1] / 2;
    const int* row = ei;
    const int* col = ei + E;

    char* w = (char*)d_ws;
    auto alloc = [&](size_t bytes) { void* q = w; w += (bytes + 255) & ~255ull; return q; };
    int*   rowptrO = (int*)  alloc((size_t)(N + 1) * 4);
    int*   rowptrI = (int*)  alloc((size_t)(N + 1) * 4);
    int2*  adjO2   = (int2*) alloc((size_t)E * 8);
    int2*  adjI2   = (int2*) alloc((size_t)E * 8);
    float* dis     = (float*)alloc((size_t)N * 4);
    float* isg1    = (float*)alloc(F1 * 4);
    float* isg2    = (float*)alloc(H * 4);
    int*   bsum    = (int*)  alloc(1024 * 4);
    unsigned short* u1   = (unsigned short*)alloc((size_t)N * F1 * 2);  // bf16(x*isg1); dead after fused1
    unsigned short* u2   = (unsigned short*)alloc((size_t)N * H * 2);   // bf16(h1*isg2)
    unsigned short* ybf1 = (unsigned short*)alloc((size_t)N * H * 2);   // bf16 xw1
    unsigned short* ybf2 = u1;                                          // bf16 xw2 aliases u1
    // cnt8/cur8 (6.4MB each) alias u2/ybf1 — dead before those are written
    int* cnt8 = (int*)u2;     // [NCOPY][2N] histogram copies
    int* cur8 = (int*)ybf1;   // [NCOPY][2N] cursor copies

    const int B = 256;
    const int cntBlocks = (E + B - 1) / B;
    const size_t n8 = (size_t)N * F1 / 8;
    const int prepBlocks = (int)((n8 + B - 1) / B);
    const int M = 2 * N;
    const int nb = (M + SCAN_EPB - 1) / SCAN_EPB;  // must be <=1024

    // ---- graph build: single-sweep count (XCD-copy histograms) + u1 prep, scan, single-sweep build ----
    hipMemsetAsync(cnt8, 0, (size_t)NCOPY * M * 4, stream);
    isg_kernel<<<1, 128, 0, stream>>>(sig1, isg1, sig2, isg2);
    count1_prep_kernel<<<cntBlocks + prepBlocks, B, 0, stream>>>(
        row, col, cnt8, E, N, cntBlocks, x, isg1, u1, n8);
    scan_partial_kernel<<<nb, SCAN_TPB, 0, stream>>>(cnt8, bsum, M);
    scan_offsets_kernel<<<1, 1024, 0, stream>>>(bsum, nb, rowptrO, rowptrI, N, E);
    scan_final_kernel<<<nb, SCAN_TPB, 0, stream>>>(cnt8, cur8, bsum, rowptrO, rowptrI, dis, N, E);
    build1_kernel<<<cntBlocks, B, 0, stream>>>(row, col, cur8, adjO2, adjI2, dis, E, N);

    // ---- layer 1 ----
    fused_mask_gemm_kernel<F1, H, 8><<<(N + 7) / 8, 512, 0, stream>>>(rowptrO, adjO2, sig1, u1, W1, ybf1, N);
    agg_relu_kernel<<<(N + 3) / 4, B, 0, stream>>>(rowptrI, adjI2, dis, ybf1, b1, u2, isg2, N);

    // ---- layer 2 ----
    fused_mask_gemm_kernel<H, NC, 8><<<(N + 7) / 8, 512, 0, stream>>>(rowptrO, adjO2, sig2, u2, W2, ybf2, N);
    agg_lsm_kernel<<<(N + 3) / 4, B, 0, stream>>>(rowptrI, adjI2, dis, ybf2, b2, out, N);
}

// Round 15
// 606.781 us; speedup vs baseline: 1.1445x; 1.1445x over previous
//
#include <hip/hip_runtime.h>
#include <cmath>

constexpr int F1 = 128;  // input features
constexpr int H  = 64;   // hidden
constexpr int NC = 40;   // classes
constexpr int NPART = 8; // edge-partitions for count/build — one partition per XCD
                         // (R14 lesson: <8 shares cnt/adj lines between XCDs -> ping-pong;
                         //  per-partition write-set ~3.2MB fits one 4MB XCD L2)

constexpr int SCAN_TPB = 256;
constexpr int SCAN_IPT = 8;
constexpr int SCAN_EPB = SCAN_TPB * SCAN_IPT;  // 2048 elements per block

// ---- bf16 helpers (RNE pack, cheap unpack) ----
__device__ inline unsigned short f2bf(float f) {
    union { float f; unsigned u; } v; v.f = f;
    return (unsigned short)((v.u + 0x7FFFu + ((v.u >> 16) & 1u)) >> 16);
}
__device__ inline float bflo(unsigned p) { union { float f; unsigned u; } v; v.u = p << 16; return v.f; }
__device__ inline float bfhi(unsigned p) { union { float f; unsigned u; } v; v.u = p & 0xFFFF0000u; return v.f; }
__device__ inline void unpack8(uint4 raw, float* d) {
    d[0] = bflo(raw.x); d[1] = bfhi(raw.x); d[2] = bflo(raw.y); d[3] = bfhi(raw.y);
    d[4] = bflo(raw.z); d[5] = bfhi(raw.z); d[6] = bflo(raw.w); d[7] = bfhi(raw.w);
}

// ---- inverse sigmas ----
__global__ void isg_kernel(const float* __restrict__ s1, float* __restrict__ i1,
                           const float* __restrict__ s2, float* __restrict__ i2) {
    int i = threadIdx.x;
    if (i < F1) i1[i] = 1.0f / s1[i];
    if (i < H)  i2[i] = 1.0f / s2[i];
}

// ---- fused: partitioned degree histogram (blocks < cntBlocks) + u1 prep (rest) ----
__global__ void count8_prep_kernel(const int* __restrict__ row, const int* __restrict__ col,
                                   int* __restrict__ cntO, int* __restrict__ cntI,
                                   int E, int chunk, int stride, int cntBlocks,
                                   const float* __restrict__ x, const float* __restrict__ isg,
                                   unsigned short* __restrict__ u, size_t n8) {
    int bid = blockIdx.x;
    if (bid < cntBlocks) {
        int p = bid & (NPART - 1);
        int gid = bid / NPART;
        unsigned lo = (unsigned)(p * chunk);
        for (int e = gid * blockDim.x + threadIdx.x; e < E; e += stride) {
            int r = row[e], c = col[e];
            if ((unsigned)r - lo < (unsigned)chunk) atomicAdd(&cntO[r], 1);
            if ((unsigned)c - lo < (unsigned)chunk) atomicAdd(&cntI[c], 1);
        }
    } else {
        size_t idx = (size_t)(bid - cntBlocks) * blockDim.x + threadIdx.x;
        if (idx >= n8) return;
        size_t base = idx * 8;
        int fk = (int)(base % (size_t)F1);
        float4 a0 = *(const float4*)&x[base];
        float4 a1 = *(const float4*)&x[base + 4];
        float4 s0 = *(const float4*)&isg[fk];
        float4 s1 = *(const float4*)&isg[fk + 4];
        uint4 p4;
        p4.x = (unsigned)f2bf(a0.x * s0.x) | ((unsigned)f2bf(a0.y * s0.y) << 16);
        p4.y = (unsigned)f2bf(a0.z * s0.z) | ((unsigned)f2bf(a0.w * s0.w) << 16);
        p4.z = (unsigned)f2bf(a1.x * s1.x) | ((unsigned)f2bf(a1.y * s1.y) << 16);
        p4.w = (unsigned)f2bf(a1.z * s1.z) | ((unsigned)f2bf(a1.w * s1.w) << 16);
        *(uint4*)&u[base] = p4;
    }
}

// ---- multi-block exclusive scan over cnt[0..M) (M = 2N: cntO|cntI contiguous) ----
__global__ void scan_partial_kernel(const int* __restrict__ cnt, int* __restrict__ bsum, int M) {
    __shared__ int red[SCAN_TPB];
    int t = threadIdx.x;
    int i0 = blockIdx.x * SCAN_EPB + t * SCAN_IPT;
    int s = 0;
#pragma unroll
    for (int k = 0; k < SCAN_IPT; ++k) {
        int i = i0 + k;
        if (i < M) s += cnt[i];
    }
    red[t] = s;
    __syncthreads();
    for (int off = SCAN_TPB / 2; off > 0; off >>= 1) {
        if (t < off) red[t] += red[t + off];
        __syncthreads();
    }
    if (t == 0) bsum[blockIdx.x] = red[0];
}

__global__ void scan_offsets_kernel(int* __restrict__ bsum, int nb,
                                    int* __restrict__ rowptrO, int* __restrict__ rowptrI,
                                    int N, int E) {
    __shared__ int sh[1024];
    int t = threadIdx.x;
    sh[t] = (t < nb) ? bsum[t] : 0;
    __syncthreads();
    for (int off = 1; off < 1024; off <<= 1) {
        int v = (t >= off) ? sh[t - off] : 0;
        __syncthreads();
        sh[t] += v;
        __syncthreads();
    }
    if (t < nb) bsum[t] = (t > 0) ? sh[t - 1] : 0;  // exclusive block offsets
    if (t == 0) { rowptrO[N] = E; rowptrI[N] = E; }
}

__global__ void scan_final_kernel(int* __restrict__ cntO, int* __restrict__ cntI,
                                  const int* __restrict__ bsum,
                                  int* __restrict__ rowptrO, int* __restrict__ rowptrI,
                                  float* __restrict__ dis, int N, int E) {
    __shared__ int sh[SCAN_TPB];
    int t = threadIdx.x;
    int M = 2 * N;
    const int* cnt = cntO;  // cntI == cntO + N (contiguous)
    int i0 = blockIdx.x * SCAN_EPB + t * SCAN_IPT;
    int cv[SCAN_IPT], pre[SCAN_IPT];
    int run = 0;
#pragma unroll
    for (int k = 0; k < SCAN_IPT; ++k) {
        int i = i0 + k;
        cv[k] = (i < M) ? cnt[i] : 0;
        pre[k] = run;
        run += cv[k];
    }
    sh[t] = run;
    __syncthreads();
    for (int off = 1; off < SCAN_TPB; off <<= 1) {
        int v = (t >= off) ? sh[t - off] : 0;
        __syncthreads();
        sh[t] += v;
        __syncthreads();
    }
    int toff = ((t > 0) ? sh[t - 1] : 0) + bsum[blockIdx.x];
#pragma unroll
    for (int k = 0; k < SCAN_IPT; ++k) {
        int i = i0 + k;
        if (i < M) {
            int val = toff + pre[k];
            if (i < N) {
                rowptrO[i] = val;
                cntO[i] = val;                         // cursor
                dis[i] = rsqrtf((float)(cv[k] + 1));   // deg includes self-loop
            } else {
                rowptrI[i - N] = val - E;
                cntI[i - N] = val - E;                 // cursor
            }
        }
    }
}

// ---- partitioned adjacency fill: adj entries carry (neighbor, norm) ----
__global__ void build8_kernel(const int* __restrict__ row, const int* __restrict__ col,
                              int* __restrict__ curO, int* __restrict__ curI,
                              int2* __restrict__ adjO2, int2* __restrict__ adjI2,
                              const float* __restrict__ dis,
                              int E, int chunk, int stride) {
    int p = blockIdx.x & (NPART - 1);
    int gid = blockIdx.x / NPART;
    unsigned lo = (unsigned)(p * chunk);
    for (int e = gid * blockDim.x + threadIdx.x; e < E; e += stride) {
        int r = row[e], c = col[e];
        bool inR = (unsigned)r - lo < (unsigned)chunk;
        bool inC = (unsigned)c - lo < (unsigned)chunk;
        if (inR | inC) {
            float nrm = dis[r] * dis[c];
            int nb = __float_as_int(nrm);
            if (inR) adjO2[atomicAdd(&curO[r], 1)] = make_int2(c, nb);
            if (inC) adjI2[atomicAdd(&curI[c], 1)] = make_int2(r, nb);
        }
    }
}

// ---- fused: mask gather (bf16 u rows; adj2 gives nbr+norm; P=2 named-scalar prefetch)
//      + apply (x = u*sigma) -> LDS Xs -> GEMM (2 waves x 4 rows, W-read amortized) ----
template<int F, int O, int R>
__global__ void fused_mask_gemm_kernel(const int* __restrict__ rowptr, const int2* __restrict__ adj2,
                                       const float* __restrict__ sig,
                                       const unsigned short* __restrict__ u,
                                       const float* __restrict__ W,
                                       unsigned short* __restrict__ Ybf, int N) {
    constexpr int NT = R * 64;
    constexpr int G = F / 8;        // lanes per row (uint4 = 8 bf16 each)
    constexpr int NPI = 64 / G;     // neighbors per wave-iteration
    __shared__ __align__(16) float Ws[F * O];
    __shared__ __align__(16) float Xs[R][F];
    int tid = threadIdx.x;
    for (int i = tid; i < F * O; i += NT) Ws[i] = W[i];
    int w = tid >> 6, lane = tid & 63;
    int h = lane / G, j = lane % G;
    int base = blockIdx.x * R;
    int r = base + w;
    if (r < N) {
        int beg = rowptr[r], end = rowptr[r + 1];
        float inv_deg = 1.0f / (float)(end - beg + 1);
        float ur[8], acc[8];
        unpack8(*(const uint4*)&u[(size_t)r * F + 8 * j], ur);
#pragma unroll
        for (int k = 0; k < 8; ++k) acc[k] = 0.0f;
        for (int t = beg; t < end; t += 2 * NPI) {
            int e0 = t + h, e1 = t + NPI + h;
            int2 a0 = adj2[min(e0, end - 1)];
            int2 a1 = adj2[min(e1, end - 1)];
            float n0 = (e0 < end) ? __int_as_float(a0.y) : 0.0f;
            float n1 = (e1 < end) ? __int_as_float(a1.y) : 0.0f;
            uint4 rw0 = *(const uint4*)&u[(size_t)a0.x * F + 8 * j];
            uint4 rw1 = *(const uint4*)&u[(size_t)a1.x * F + 8 * j];
            float uc[8];
            unpack8(rw0, uc);
#pragma unroll
            for (int q = 0; q < 8; ++q) {
                float d = uc[q] - ur[q];
                acc[q] = fmaf(n0 * d, d, acc[q]);
            }
            unpack8(rw1, uc);
#pragma unroll
            for (int q = 0; q < 8; ++q) {
                float d = uc[q] - ur[q];
                acc[q] = fmaf(n1 * d, d, acc[q]);
            }
        }
#pragma unroll
        for (int off = G; off < 64; off <<= 1) {
#pragma unroll
            for (int k = 0; k < 8; ++k) acc[k] += __shfl_xor(acc[k], off);
        }
        if (h == 0) {
            float4 s0 = *(const float4*)&sig[8 * j];
            float4 s1 = *(const float4*)&sig[8 * j + 4];
            float sg[8] = {s0.x, s0.y, s0.z, s0.w, s1.x, s1.y, s1.z, s1.w};
            float xm[8];
#pragma unroll
            for (int k = 0; k < 8; ++k) xm[k] = ur[k] * sg[k] * expf(-acc[k] * inv_deg);
            *(float4*)&Xs[w][8 * j]     = make_float4(xm[0], xm[1], xm[2], xm[3]);
            *(float4*)&Xs[w][8 * j + 4] = make_float4(xm[4], xm[5], xm[6], xm[7]);
        }
    } else if (h == 0) {
        *(float4*)&Xs[w][8 * j]     = make_float4(0.f, 0.f, 0.f, 0.f);
        *(float4*)&Xs[w][8 * j + 4] = make_float4(0.f, 0.f, 0.f, 0.f);
    }
    __syncthreads();
    // GEMM: waves 0,1 each compute 4 rows; lane = output column.
    if (w < 2) {
        int r0 = base + 4 * w;
        if (r0 < N && lane < O) {
            float a0 = 0.f, a1 = 0.f, a2 = 0.f, a3 = 0.f;
#pragma unroll
            for (int fq = 0; fq < F / 4; ++fq) {
                float4 x0 = *(const float4*)&Xs[4 * w + 0][4 * fq];
                float4 x1 = *(const float4*)&Xs[4 * w + 1][4 * fq];
                float4 x2 = *(const float4*)&Xs[4 * w + 2][4 * fq];
                float4 x3 = *(const float4*)&Xs[4 * w + 3][4 * fq];
                float w0 = Ws[(4 * fq + 0) * O + lane];
                float w1 = Ws[(4 * fq + 1) * O + lane];
                float w2 = Ws[(4 * fq + 2) * O + lane];
                float w3 = Ws[(4 * fq + 3) * O + lane];
                a0 = fmaf(x0.x, w0, a0); a0 = fmaf(x0.y, w1, a0); a0 = fmaf(x0.z, w2, a0); a0 = fmaf(x0.w, w3, a0);
                a1 = fmaf(x1.x, w0, a1); a1 = fmaf(x1.y, w1, a1); a1 = fmaf(x1.z, w2, a1); a1 = fmaf(x1.w, w3, a1);
                a2 = fmaf(x2.x, w0, a2); a2 = fmaf(x2.y, w1, a2); a2 = fmaf(x2.z, w2, a2); a2 = fmaf(x2.w, w3, a2);
                a3 = fmaf(x3.x, w0, a3); a3 = fmaf(x3.y, w1, a3); a3 = fmaf(x3.z, w2, a3); a3 = fmaf(x3.w, w3, a3);
            }
            float o0 = __shfl_xor(a0, 1);
            float o1 = __shfl_xor(a1, 1);
            float o2 = __shfl_xor(a2, 1);
            float o3 = __shfl_xor(a3, 1);
            if (!(lane & 1)) {
                *(unsigned*)&Ybf[(size_t)r0 * O + lane] = (unsigned)f2bf(a0) | ((unsigned)f2bf(o0) << 16);
                if (r0 + 1 < N) *(unsigned*)&Ybf[(size_t)(r0 + 1) * O + lane] = (unsigned)f2bf(a1) | ((unsigned)f2bf(o1) << 16);
                if (r0 + 2 < N) *(unsigned*)&Ybf[(size_t)(r0 + 2) * O + lane] = (unsigned)f2bf(a2) | ((unsigned)f2bf(o2) << 16);
                if (r0 + 3 < N) *(unsigned*)&Ybf[(size_t)(r0 + 3) * O + lane] = (unsigned)f2bf(a3) | ((unsigned)f2bf(o3) << 16);
            }
        }
    }
}

// ---- agg layer1: h = relu(sum nrm*xw_bf16 + dis^2*xw_self + b); writes ONLY u2=bf16(h*isg2) ----
__global__ void agg_relu_kernel(const int* __restrict__ rowptr, const int2* __restrict__ adj2,
                                const float* __restrict__ dis, const unsigned short* __restrict__ ybf,
                                const float* __restrict__ bias,
                                unsigned short* __restrict__ u2, const float* __restrict__ isg2, int N) {
    int c = blockIdx.x * (blockDim.x >> 6) + (threadIdx.x >> 6);
    if (c >= N) return;
    int lane = threadIdx.x & 63;
    int h = lane >> 3, j = lane & 7;
    int beg = rowptr[c], end = rowptr[c + 1];
    float acc[8];
#pragma unroll
    for (int k = 0; k < 8; ++k) acc[k] = 0.0f;
    for (int t = beg; t < end; t += 16) {
        int e0 = t + h, e1 = t + 8 + h;
        int2 a0 = adj2[min(e0, end - 1)];
        int2 a1 = adj2[min(e1, end - 1)];
        float n0 = (e0 < end) ? __int_as_float(a0.y) : 0.0f;
        float n1 = (e1 < end) ? __int_as_float(a1.y) : 0.0f;
        uint4 rw0 = *(const uint4*)&ybf[(size_t)a0.x * H + 8 * j];
        uint4 rw1 = *(const uint4*)&ybf[(size_t)a1.x * H + 8 * j];
        float v[8];
        unpack8(rw0, v);
#pragma unroll
        for (int q = 0; q < 8; ++q) acc[q] = fmaf(n0, v[q], acc[q]);
        unpack8(rw1, v);
#pragma unroll
        for (int q = 0; q < 8; ++q) acc[q] = fmaf(n1, v[q], acc[q]);
    }
#pragma unroll
    for (int off = 8; off < 64; off <<= 1) {
#pragma unroll
        for (int k = 0; k < 8; ++k) acc[k] += __shfl_xor(acc[k], off);
    }
    if (h == 0) {
        float dc = dis[c];
        float sv[8];
        unpack8(*(const uint4*)&ybf[(size_t)c * H + 8 * j], sv);
        float4 b0 = *(const float4*)&bias[8 * j];
        float4 b1v = *(const float4*)&bias[8 * j + 4];
        float bb[8] = {b0.x, b0.y, b0.z, b0.w, b1v.x, b1v.y, b1v.z, b1v.w};
        float4 s0 = *(const float4*)&isg2[8 * j];
        float4 s1 = *(const float4*)&isg2[8 * j + 4];
        float sg[8] = {s0.x, s0.y, s0.z, s0.w, s1.x, s1.y, s1.z, s1.w};
        float hv[8];
        float d2 = dc * dc;
#pragma unroll
        for (int k = 0; k < 8; ++k) hv[k] = fmaxf(fmaf(d2, sv[k], acc[k]) + bb[k], 0.0f);
        uint4 p;
        p.x = (unsigned)f2bf(hv[0] * sg[0]) | ((unsigned)f2bf(hv[1] * sg[1]) << 16);
        p.y = (unsigned)f2bf(hv[2] * sg[2]) | ((unsigned)f2bf(hv[3] * sg[3]) << 16);
        p.z = (unsigned)f2bf(hv[4] * sg[4]) | ((unsigned)f2bf(hv[5] * sg[5]) << 16);
        p.w = (unsigned)f2bf(hv[6] * sg[6]) | ((unsigned)f2bf(hv[7] * sg[7]) << 16);
        *(uint4*)&u2[(size_t)c * H + 8 * j] = p;
    }
}

// ---- agg layer2: out = log_softmax(sum nrm*xw2_bf16 + dis^2*self + b) over NC=40 ----
__global__ void agg_lsm_kernel(const int* __restrict__ rowptr, const int2* __restrict__ adj2,
                               const float* __restrict__ dis, const unsigned short* __restrict__ ybf,
                               const float* __restrict__ bias, float* __restrict__ out, int N) {
    int c = blockIdx.x * (blockDim.x >> 6) + (threadIdx.x >> 6);
    if (c >= N) return;
    int lane = threadIdx.x & 63;
    int h = lane >> 4, j = lane & 15;
    bool active = j < 10;
    int beg = rowptr[c], end = rowptr[c + 1];
    float a[4] = {0.f, 0.f, 0.f, 0.f};
    for (int t = beg; t < end; t += 8) {
        int e0 = t + h, e1 = t + 4 + h;
        int2 a0 = adj2[min(e0, end - 1)];
        int2 a1 = adj2[min(e1, end - 1)];
        float n0 = (e0 < end) ? __int_as_float(a0.y) : 0.0f;
        float n1 = (e1 < end) ? __int_as_float(a1.y) : 0.0f;
        uint2 rw0 = active ? *(const uint2*)&ybf[(size_t)a0.x * NC + 4 * j] : make_uint2(0u, 0u);
        uint2 rw1 = active ? *(const uint2*)&ybf[(size_t)a1.x * NC + 4 * j] : make_uint2(0u, 0u);
        a[0] = fmaf(n0, bflo(rw0.x), a[0]); a[1] = fmaf(n0, bfhi(rw0.x), a[1]);
        a[2] = fmaf(n0, bflo(rw0.y), a[2]); a[3] = fmaf(n0, bfhi(rw0.y), a[3]);
        a[0] = fmaf(n1, bflo(rw1.x), a[0]); a[1] = fmaf(n1, bfhi(rw1.x), a[1]);
        a[2] = fmaf(n1, bflo(rw1.y), a[2]); a[3] = fmaf(n1, bfhi(rw1.y), a[3]);
    }
#pragma unroll
    for (int off = 16; off < 64; off <<= 1) {
#pragma unroll
        for (int k = 0; k < 4; ++k) a[k] += __shfl_xor(a[k], off);
    }
    bool wr = (h == 0) && active;
    float v[4] = {-INFINITY, -INFINITY, -INFINITY, -INFINITY};
    if (wr) {
        float dc = dis[c];
        uint2 sr = *(const uint2*)&ybf[(size_t)c * NC + 4 * j];
        float sv[4] = {bflo(sr.x), bfhi(sr.x), bflo(sr.y), bfhi(sr.y)};
        float4 bb = *(const float4*)&bias[4 * j];
        float b4[4] = {bb.x, bb.y, bb.z, bb.w};
        float d2 = dc * dc;
#pragma unroll
        for (int k = 0; k < 4; ++k) v[k] = fmaf(d2, sv[k], a[k]) + b4[k];
    }
    float m = fmaxf(fmaxf(v[0], v[1]), fmaxf(v[2], v[3]));
#pragma unroll
    for (int off = 8; off > 0; off >>= 1) m = fmaxf(m, __shfl_xor(m, off));
    float s = wr ? (expf(v[0] - m) + expf(v[1] - m) + expf(v[2] - m) + expf(v[3] - m)) : 0.0f;
#pragma unroll
    for (int off = 8; off > 0; off >>= 1) s += __shfl_xor(s, off);
    float mls = m + logf(s);
    if (wr)
        *(float4*)&out[(size_t)c * NC + 4 * j] = make_float4(v[0] - mls, v[1] - mls, v[2] - mls, v[3] - mls);
}

extern "C" void kernel_launch(void* const* d_in, const int* in_sizes, int n_in,
                              void* d_out, int out_size, void* d_ws, size_t ws_size,
                              hipStream_t stream) {
    const float* x    = (const float*)d_in[0];
    const int*   ei   = (const int*)  d_in[1];
    const float* sig1 = (const float*)d_in[2];
    const float* W1   = (const float*)d_in[3];
    const float* b1   = (const float*)d_in[4];
    const float* sig2 = (const float*)d_in[5];
    const float* W2   = (const float*)d_in[6];
    const float* b2   = (const float*)d_in[7];
    float* out = (float*)d_out;

    const int N = in_sizes[0] / F1;
    const int E = in_sizes[1] / 2;
    const int* row = ei;
    const int* col = ei + E;

    char* w = (char*)d_ws;
    auto alloc = [&](size_t bytes) { void* q = w; w += (bytes + 255) & ~255ull; return q; };
    int*   cntO    = (int*)  alloc((size_t)2 * N * 4);
    int*   cntI    = cntO + N;
    int*   rowptrO = (int*)  alloc((size_t)(N + 1) * 4);
    int*   rowptrI = (int*)  alloc((size_t)(N + 1) * 4);
    int2*  adjO2   = (int2*) alloc((size_t)E * 8);
    int2*  adjI2   = (int2*) alloc((size_t)E * 8);
    float* dis     = (float*)alloc((size_t)N * 4);
    float* isg1    = (float*)alloc(F1 * 4);
    float* isg2    = (float*)alloc(H * 4);
    int*   bsum    = (int*)  alloc(1024 * 4);
    unsigned short* u1   = (unsigned short*)alloc((size_t)N * F1 * 2);  // bf16(x*isg1); dead after fused1
    unsigned short* u2   = (unsigned short*)alloc((size_t)N * H * 2);   // bf16(h1*isg2)
    unsigned short* ybf1 = (unsigned short*)alloc((size_t)N * H * 2);   // bf16 xw1
    unsigned short* ybf2 = u1;                                          // bf16 xw2 aliases u1

    const int B = 256;
    const int chunk = (N + NPART - 1) / NPART;
    const int TOTB = 8192;                       // total worker blocks for count/build
    const int stride8 = (TOTB / NPART) * B;
    const size_t n8 = (size_t)N * F1 / 8;
    const int prepBlocks = (int)((n8 + B - 1) / B);
    const int M = 2 * N;
    const int nb = (M + SCAN_EPB - 1) / SCAN_EPB;  // must be <=1024

    // ---- graph build (+ u1 prep overlapped into count) ----
    hipMemsetAsync(cntO, 0, (size_t)2 * N * 4, stream);
    isg_kernel<<<1, 128, 0, stream>>>(sig1, isg1, sig2, isg2);
    count8_prep_kernel<<<TOTB + prepBlocks, B, 0, stream>>>(
        row, col, cntO, cntI, E, chunk, stride8, TOTB, x, isg1, u1, n8);
    scan_partial_kernel<<<nb, SCAN_TPB, 0, stream>>>(cntO, bsum, M);
    scan_offsets_kernel<<<1, 1024, 0, stream>>>(bsum, nb, rowptrO, rowptrI, N, E);
    scan_final_kernel<<<nb, SCAN_TPB, 0, stream>>>(cntO, cntI, bsum, rowptrO, rowptrI, dis, N, E);
    build8_kernel<<<TOTB, B, 0, stream>>>(row, col, cntO, cntI, adjO2, adjI2, dis, E, chunk, stride8);

    // ---- layer 1 ----
    fused_mask_gemm_kernel<F1, H, 8><<<(N + 7) / 8, 512, 0, stream>>>(rowptrO, adjO2, sig1, u1, W1, ybf1, N);
    agg_relu_kernel<<<(N + 3) / 4, B, 0, stream>>>(rowptrI, adjI2, dis, ybf1, b1, u2, isg2, N);

    // ---- layer 2 ----
    fused_mask_gemm_kernel<H, NC, 8><<<(N + 7) / 8, 512, 0, stream>>>(rowptrO, adjO2, sig2, u2, W2, ybf2, N);
    agg_lsm_kernel<<<(N + 3) / 4, B, 0, stream>>>(rowptrI, adjI2, dis, ybf2, b2, out, N);
}